// Round 6
// baseline (97.826 us; speedup 1.0000x reference)
//
#include <hip/hip_runtime.h>

// S4D kernel materialization:
//   dt = exp(log_dt[h]) ; A = -exp(log_A_real) + i*A_imag
//   dtA = A*dt ; w = exp(dtA) ; Cc = C*(w-1)/A
//   K[h,l] = 2 * Re( sum_n Cc[h,n] * w[h,n]^l )
//
// R6 = DIAGNOSTIC ROUND. Kernel is faster than the harness's 41.5us poison
// fills, so it never appears in rocprof top-5. REPS=3 repeats the main loop
// (acc accumulates 3x, store scales by 1/3; opaque asm on LDS indices blocks
// CSE) to force the kernel to top-1 and capture VALUBusy / Occupancy / VGPR /
// LDS-conflict counters. Also: float4-packed LDS tables -> 2x ds_read_b128
// per mode (was 6 narrow reads + 2 readfirstlane).

static __device__ __forceinline__ float2 cmul(float2 a, float2 b) {
    return make_float2(fmaf(a.x, b.x, -(a.y * b.y)),
                       fmaf(a.x, b.y,   a.y * b.x));
}

template <int N2, int BLK, int J, int REPS>
__global__ __launch_bounds__(BLK, 8) void s4d_kernel(
    const float* __restrict__ C,
    const float* __restrict__ log_dt,
    const float* __restrict__ log_A_real,
    const float* __restrict__ A_imag,
    float* __restrict__ K,
    int L)
{
    __shared__ float4 s_lop[N2][16];  // (lo.x, lo.y, lo2.x, lo2.y)
    __shared__ float4 s_hip[N2][16];  // (hi.x, hi.y, aW, bW)

    const int h = blockIdx.x;
    const int y = blockIdx.y;
    const int lbase = y * (BLK * J);
    const int t = threadIdx.x;

    if (t < N2) {
        const int n = t;
        const float dt  = expf(log_dt[h]);
        const float Are = -expf(log_A_real[h * N2 + n]);
        const float Aim = A_imag[h * N2 + n];
        const float dre = Are * dt;
        const float dim = Aim * dt;           // |dim| <= ~9.7 rad: fast path
        float sw, cw;
        sincosf(dim, &sw, &cw);
        const float er = expf(dre);
        const float2 w = make_float2(er * cw, er * sw);
        // 2*Cc = 2*C*(w-1)/A
        const float nre = w.x - 1.0f;
        const float nim = w.y;
        const float inv = 1.0f / (Are * Are + Aim * Aim);
        const float qre = (nre * Are + nim * Aim) * inv;
        const float qim = (nim * Are - nre * Aim) * inv;
        const float c2  = 2.0f * C[h * N2 + n];
        // powers of w by squaring
        const float2 w2   = cmul(w,    w);
        const float2 w4   = cmul(w2,   w2);
        const float2 w8   = cmul(w4,   w4);
        const float2 w16  = cmul(w8,   w8);
        const float2 w32  = cmul(w16,  w16);
        const float2 w64  = cmul(w32,  w32);
        const float2 w128 = cmul(w64,  w64);
        const float2 W    = cmul(w128, w128);   // w^256 == w^BLK
        const float aW = W.x + W.x;
        const float bW = -fmaf(W.x, W.x, W.y * W.y);
        // hi table: (w^16)^k with aW,bW replicated
        float2 curh = make_float2(1.0f, 0.0f);
#pragma unroll
        for (int k = 0; k < 16; ++k) {
            s_hip[n][k] = make_float4(curh.x, curh.y, aW, bW);
            curh = cmul(curh, w16);
        }
        // w^lbase = W^(J*y) by binary pow (block-uniform small loop)
        float2 P = make_float2(1.0f, 0.0f);
        float2 base = W;
        int e = J * y;
        while (e) { if (e & 1) P = cmul(P, base); base = cmul(base, base); e >>= 1; }
        float2 cur  = cmul(make_float2(c2 * qre, c2 * qim), P);  // 2Cc * w^lbase
        float2 cur2 = cmul(cur, W);
#pragma unroll
        for (int k = 0; k < 16; ++k) {
            s_lop[n][k] = make_float4(cur.x, cur.y, cur2.x, cur2.y);
            cur  = cmul(cur,  w);
            cur2 = cmul(cur2, w);
        }
    }
    __syncthreads();

    float acc[J];
#pragma unroll
    for (int j = 0; j < J; ++j) acc[j] = 0.0f;

    const int tlo = t & 15;
    const int thi = t >> 4;

    for (int r = 0; r < REPS; ++r) {
        // Opaque indices: forces each rep to re-execute loads + math (no CSE).
        int tlo2 = tlo, thi2 = thi;
        asm volatile("" : "+v"(tlo2), "+v"(thi2));

#pragma unroll 2
        for (int n = 0; n < N2; ++n) {
            const float4 lp = s_lop[n][tlo2];
            const float4 hp = s_hip[n][thi2];

            float x0 = fmaf(lp.x, hp.x, -(lp.y * hp.y));   // Re(2Cc w^(lbase+t))
            float x1 = fmaf(lp.z, hp.x, -(lp.w * hp.y));   // Re(... * W)
            acc[0] += x0;
            acc[1] += x1;
#pragma unroll
            for (int j = 2; j < J; ++j) {
                const float x2 = fmaf(hp.z, x1, hp.w * x0);  // 2Re(W)x1 - |W|^2 x0
                acc[j] += x2;
                x0 = x1;
                x1 = x2;
            }
        }
    }

    const float scale = 1.0f / (float)REPS;
    float* __restrict__ outp = K + (size_t)h * (size_t)L + lbase + t;
#pragma unroll
    for (int j = 0; j < J; ++j) {
        const int l = lbase + j * BLK + t;
        if (l < L) outp[(size_t)j * BLK] = acc[j] * scale;
    }
}

extern "C" void kernel_launch(void* const* d_in, const int* in_sizes, int n_in,
                              void* d_out, int out_size, void* d_ws, size_t ws_size,
                              hipStream_t stream)
{
    const float* C          = (const float*)d_in[0];
    const float* log_dt     = (const float*)d_in[1];
    const float* log_A_real = (const float*)d_in[2];
    const float* A_imag     = (const float*)d_in[3];
    float* K = (float*)d_out;

    const int H   = in_sizes[1];           // 1024
    const int N2v = in_sizes[0] / H;       // 32
    const int L   = out_size / H;          // 4096
    constexpr int BLK  = 256;
    constexpr int J    = 8;                // samples per thread
    constexpr int REPS = 3;                // DIAGNOSTIC: x3 main loop for rocprof visibility
    const int gy = (L + BLK * J - 1) / (BLK * J);

    if (N2v != 32) return;
    dim3 grid((unsigned)H, (unsigned)gy);
    s4d_kernel<32, BLK, J, REPS><<<grid, BLK, 0, stream>>>(
        C, log_dt, log_A_real, A_imag, K, L);
}

// Round 7
// 78.201 us; speedup vs baseline: 1.2509x; 1.2509x over previous
//
#include <hip/hip_runtime.h>

// S4D kernel materialization:
//   dt = exp(log_dt[h]) ; A = -exp(log_A_real) + i*A_imag
//   dtA = A*dt ; w = exp(dtA) ; Cc = C*(w-1)/A
//   K[h,l] = 2 * Re( sum_n Cc[h,n] * w[h,n]^l )
//
// R6 diagnosis: main loop LDS-pipe-bound (64 ds_read_b128/wave/pass ~= 10us),
// setup ~8-10us serial on 1 wave. R7:
//  (1) J=16, single launch: 2 b128 reads serve 16 samples -> LDS traffic halves,
//      LDS (~5.5us) and VALU (~5.3us) pipes balanced.
//  (2) Parallel table build: all 256 threads, 2 lo + 2 hi entries each via
//      selected-factor binary pow (<=3 chained cmuls). Setup ~0.2us.
// Main loop: Chebyshev x_{j+1} = 2Re(W) x_j - |W|^2 x_{j-1}, W = w^256.

static __device__ __forceinline__ float2 cmul(float2 a, float2 b) {
    return make_float2(fmaf(a.x, b.x, -(a.y * b.y)),
                       fmaf(a.x, b.y,   a.y * b.x));
}

template <int N2, int BLK, int J>
__global__ __launch_bounds__(BLK, 4) void s4d_kernel(
    const float* __restrict__ C,
    const float* __restrict__ log_dt,
    const float* __restrict__ log_A_real,
    const float* __restrict__ A_imag,
    float* __restrict__ K,
    int L)
{
    __shared__ float4 s_lop[N2][16];  // (lo.x, lo.y, (lo*W).x, (lo*W).y), lo = 2Cc*w^(lbase+k)
    __shared__ float4 s_hip[N2][16];  // ((w^16)^k re, im, 2Re(W), -|W|^2)

    const int h = blockIdx.x;
    const int y = blockIdx.y;
    const int lbase = y * (BLK * J);
    const int t = threadIdx.x;

    // ---- Parallel setup: thread t builds entries (n, kk) and (n, kk+1) ----
    {
        const int n  = t >> 3;         // mode 0..31 (8 threads per mode)
        const int e  = t & 7;
        const int kk = e * 2;          // 0,2,...,14

        const float dt  = expf(log_dt[h]);
        const float Are = -expf(log_A_real[h * N2 + n]);
        const float Aim = A_imag[h * N2 + n];
        const float dre = Are * dt;
        const float dim = Aim * dt;    // |dim| <= ~9.7 rad: fast sincos path
        float sw, cw;
        sincosf(dim, &sw, &cw);
        const float er = expf(dre);
        const float2 w = make_float2(er * cw, er * sw);
        // 2*Cc = 2*C*(w-1)/A
        const float nre = w.x - 1.0f;
        const float nim = w.y;
        const float inv = 1.0f / (Are * Are + Aim * Aim);
        const float2 c  = make_float2(
            2.0f * C[h * N2 + n] * ((nre * Are + nim * Aim) * inv),
            2.0f * C[h * N2 + n] * ((nim * Are - nre * Aim) * inv));
        // powers of w by squaring
        const float2 w2   = cmul(w,    w);
        const float2 w4   = cmul(w2,   w2);
        const float2 w8   = cmul(w4,   w4);
        const float2 w16  = cmul(w8,   w8);
        const float2 w32  = cmul(w16,  w16);
        const float2 w64  = cmul(w32,  w32);
        const float2 w128 = cmul(w64,  w64);
        const float2 W    = cmul(w128, w128);   // w^256 == w^BLK
        const float aW = W.x + W.x;
        const float bW = -fmaf(W.x, W.x, W.y * W.y);

        const float2 ONE = make_float2(1.0f, 0.0f);
        // w^kk = (w^2)^e, e<8: product of selected {w2,w4,w8}
        const float2 f1 = (e & 1) ? w2 : ONE;
        const float2 f2 = (e & 2) ? w4 : ONE;
        const float2 f3 = (e & 4) ? w8 : ONE;
        const float2 pk = cmul(cmul(f1, f2), f3);
        // (w^16)^kk = (w^32)^e
        const float2 g1 = (e & 1) ? w32  : ONE;
        const float2 g2 = (e & 2) ? w64  : ONE;
        const float2 g3 = (e & 4) ? w128 : ONE;
        const float2 qk = cmul(cmul(g1, g2), g3);

        // w^lbase = W^(J*y), block-uniform binary pow (no-op when y==0)
        float2 P = ONE;
        {
            float2 base = W;
            int ee = J * y;
            while (ee) { if (ee & 1) P = cmul(P, base); base = cmul(base, base); ee >>= 1; }
        }

        const float2 lo0  = cmul(cmul(c, P), pk);   // 2Cc * w^(lbase+kk)
        const float2 lo1  = cmul(lo0, w);
        const float2 lo20 = cmul(lo0, W);
        const float2 lo21 = cmul(lo1, W);
        s_lop[n][kk]     = make_float4(lo0.x, lo0.y, lo20.x, lo20.y);
        s_lop[n][kk + 1] = make_float4(lo1.x, lo1.y, lo21.x, lo21.y);

        const float2 hi1 = cmul(qk, w16);
        s_hip[n][kk]     = make_float4(qk.x,  qk.y,  aW, bW);
        s_hip[n][kk + 1] = make_float4(hi1.x, hi1.y, aW, bW);
    }
    __syncthreads();

    float acc[J];
#pragma unroll
    for (int j = 0; j < J; ++j) acc[j] = 0.0f;

    const int tlo = t & 15;
    const int thi = t >> 4;

#pragma unroll 2
    for (int n = 0; n < N2; ++n) {
        const float4 lp = s_lop[n][tlo];
        const float4 hp = s_hip[n][thi];

        float x0 = fmaf(lp.x, hp.x, -(lp.y * hp.y));   // Re(2Cc w^(lbase+t))
        float x1 = fmaf(lp.z, hp.x, -(lp.w * hp.y));   // Re(... * W)
        acc[0] += x0;
        acc[1] += x1;
#pragma unroll
        for (int j = 2; j < J; ++j) {
            const float x2 = fmaf(hp.z, x1, hp.w * x0);  // 2Re(W)x1 - |W|^2 x0
            acc[j] += x2;
            x0 = x1;
            x1 = x2;
        }
    }

    float* __restrict__ outp = K + (size_t)h * (size_t)L + lbase + t;
#pragma unroll
    for (int j = 0; j < J; ++j) {
        const int l = lbase + j * BLK + t;
        if (l < L) outp[(size_t)j * BLK] = acc[j];
    }
}

extern "C" void kernel_launch(void* const* d_in, const int* in_sizes, int n_in,
                              void* d_out, int out_size, void* d_ws, size_t ws_size,
                              hipStream_t stream)
{
    const float* C          = (const float*)d_in[0];
    const float* log_dt     = (const float*)d_in[1];
    const float* log_A_real = (const float*)d_in[2];
    const float* A_imag     = (const float*)d_in[3];
    float* K = (float*)d_out;

    const int H   = in_sizes[1];           // 1024
    const int N2v = in_sizes[0] / H;       // 32
    const int L   = out_size / H;          // 4096
    constexpr int BLK = 256;
    constexpr int J   = 16;                // samples per thread
    const int gy = (L + BLK * J - 1) / (BLK * J);   // 1 for L=4096

    if (N2v != 32) return;
    dim3 grid((unsigned)H, (unsigned)gy);
    s4d_kernel<32, BLK, J><<<grid, BLK, 0, stream>>>(
        C, log_dt, log_A_real, A_imag, K, L);
}